// Round 7
// baseline (155.981 us; speedup 1.0000x reference)
//
#include <hip/hip_runtime.h>
#include <hip/hip_bf16.h>

#define IMG_W 1024
#define IMG_H 1024
#define TH    8           // output rows per block: 2048 blocks
#define VX    4           // pixels per thread (float4)
#define NTHREADS 256      // full row width per block

#define ALPHA_ 0.85f
#define BETA_  0.15f
#define C1_    (0.01f * 0.01f)
#define C2_    (0.03f * 0.03f)

// Sums-domain SSIM constants (numerator/denominator both scaled by 81).
#define K1_   (81.0f * C1_)          // 0.0081
#define K2_   (81.0f * C2_)          // 0.0729
#define K12_  (K1_ + K2_)            // 0.081

// Coarse phase pin (kept from R4; harmless).
#define PIN() __builtin_amdgcn_sched_barrier(0)

// Per-row raw buffer: vector body + 2 uniform-broadcast strip-edge values
// per tensor. NO strided gathers (R0-R6 issued 4 stride-16B gathers per row
// = ~2/3 of all TA address-processing; the one invariant across all rounds).
struct RowBuf { float4 p4, t4; float pl, pr, tl, tr; };

// Per-row horizontal 3-sum stats for VX pixels: 20 floats.
struct RowS { float p[VX], t[VX], pp[VX], tt[VX], pt[VX]; };

__device__ __forceinline__ void rzero(RowS& h) {
#pragma unroll
    for (int j = 0; j < VX; ++j) {
        h.p[j] = 0.f; h.t[j] = 0.f; h.pp[j] = 0.f; h.tt[j] = 0.f; h.pt[j] = 0.f;
    }
}

// Load phase: pure loads, no value-uses (so waits stay at consume site).
// xsl/xsr are WAVE-UNIFORM clamped strip-edge addresses -> broadcast loads
// (1 cache line, no divergence).
__device__ __forceinline__ void load_rowb(const float* __restrict__ Pr,
                                          const float* __restrict__ Tr,
                                          int x, int xsl, int xsr, RowBuf& b) {
    b.p4 = *reinterpret_cast<const float4*>(Pr + x);
    b.t4 = *reinterpret_cast<const float4*>(Tr + x);
    b.pl = Pr[xsl]; b.tl = Tr[xsl];
    b.pr = Pr[xsr]; b.tr = Tr[xsr];
}

__device__ __forceinline__ void zero_rowb(RowBuf& b) {
    b.p4 = make_float4(0.f, 0.f, 0.f, 0.f);
    b.t4 = make_float4(0.f, 0.f, 0.f, 0.f);
    b.pl = b.pr = b.tl = b.tr = 0.f;
}

// Consume phase: expand a RowBuf into the 6-wide window via wave shuffles.
// pv[0] = pixel x-1 = neighbor lane's p4.w (lane 0: broadcast pl);
// pv[5] = pixel x+4 = neighbor lane's p4.x (lane 63: broadcast pr).
// Image-edge zeroing applied here (matches zero-pad semantics).
__device__ __forceinline__ void expand6(const RowBuf& b, int lane, int x,
                                        float pv[6], float tv[6]) {
    pv[1] = b.p4.x; pv[2] = b.p4.y; pv[3] = b.p4.z; pv[4] = b.p4.w;
    tv[1] = b.t4.x; tv[2] = b.t4.y; tv[3] = b.t4.z; tv[4] = b.t4.w;
    float pu = __shfl_up(b.p4.w, 1, 64);
    float tu = __shfl_up(b.t4.w, 1, 64);
    float pd = __shfl_down(b.p4.x, 1, 64);
    float td = __shfl_down(b.t4.x, 1, 64);
    pv[0] = (lane == 0)  ? b.pl : pu;
    tv[0] = (lane == 0)  ? b.tl : tu;
    pv[5] = (lane == 63) ? b.pr : pd;
    tv[5] = (lane == 63) ? b.tr : td;
    if (x == 0)          { pv[0] = 0.f; tv[0] = 0.f; }   // image left edge
    if (x + VX >= IMG_W) { pv[5] = 0.f; tv[5] = 0.f; }   // image right edge
}

__device__ __forceinline__ void hsum(const float pv[6], const float tv[6], RowS& h) {
#pragma unroll
    for (int j = 0; j < VX; ++j) {
        const float a = pv[j], b = pv[j + 1], c = pv[j + 2];
        const float u = tv[j], v = tv[j + 1], w = tv[j + 2];
        h.p[j]  = a + b + c;
        h.t[j]  = u + v + w;
        h.pp[j] = a * a + b * b + c * c;
        h.tt[j] = u * u + v * v + w * w;
        h.pt[j] = a * u + b * v + c * w;
    }
}

__device__ __forceinline__ void add_l1(const float pv[6], const float tv[6],
                                       float& l1_acc) {
#pragma unroll
    for (int k = 1; k <= VX; ++k) l1_acc += fabsf(pv[k] - tv[k]);
}

// Consume one row: emit SSIM for the output row above it and roll the
// vertical window state (AB = rowstats(y-1)+rowstats(y), Bp = rowstats(y)).
__device__ __forceinline__ void compute_row(const float pv[6], const float tv[6],
                                            RowS& AB, RowS& Bp, float& ssim_acc) {
#pragma unroll
    for (int j = 0; j < VX; ++j) {
        const float a = pv[j], b = pv[j + 1], c = pv[j + 2];
        const float u = tv[j], v = tv[j + 1], w = tv[j + 2];
        const float cp  = a + b + c;
        const float ct  = u + v + w;
        const float cpp = a * a + b * b + c * c;
        const float ctt = u * u + v * v + w * w;
        const float cpt = a * u + b * v + c * w;

        const float Sp  = AB.p[j]  + cp;
        const float St  = AB.t[j]  + ct;
        const float Spp = AB.pp[j] + cpp;
        const float Stt = AB.tt[j] + ctt;
        const float Spt = AB.pt[j] + cpt;

        AB.p[j]  = Bp.p[j]  + cp;  Bp.p[j]  = cp;
        AB.t[j]  = Bp.t[j]  + ct;  Bp.t[j]  = ct;
        AB.pp[j] = Bp.pp[j] + cpp; Bp.pp[j] = cpp;
        AB.tt[j] = Bp.tt[j] + ctt; Bp.tt[j] = ctt;
        AB.pt[j] = Bp.pt[j] + cpt; Bp.pt[j] = cpt;

        // sums-domain SSIM (x81^2 in both numerator and denominator)
        const float SpSt = Sp * St;
        const float A2 = fmaf(2.0f, SpSt, K1_);
        const float B2 = fmaf(-2.0f, SpSt, fmaf(18.0f, Spt, K2_));
        const float n  = A2 * B2;
        const float D1 = fmaf(Sp, Sp, fmaf(St, St, K1_));
        const float D2 = fmaf(9.0f, Spp + Stt, K12_) - D1;
        const float d  = D1 * D2;
        const float ssim = n * __builtin_amdgcn_rcpf(d);  // d >= 81^2*C1*C2 > 0
        float vcl = fmaf(-0.5f, ssim, 0.5f);
        vcl = fminf(fmaxf(vcl, 0.0f), 1.0f);
        ssim_acc += vcl;
    }
}

// R7: R4's proven skeleton (best main dur: 44.7us) with two changes:
//  1. Shuffle-halo: per-row VMEM drops from {2 dwordx4 + 4 stride-16B
//     gathers (~16 txns each)} to {2 dwordx4 + 4 uniform broadcast loads
//     (1 txn each)}. Gather txns/row ~96 -> ~36 (worst-case TA model 8x).
//  2. XCD-chunked bijective swizzle (T1): each XCD owns 2 contiguous
//     images -> vertical-halo re-reads are same-XCD-L2 hits.
template <int MODE>
__global__ void __launch_bounds__(NTHREADS)
ssim_l1_kernel(const float* __restrict__ pred, const float* __restrict__ tgt,
               float* __restrict__ ws) {
    const int tid  = threadIdx.x;
    const int lane = tid & 63;
    const int x    = tid * VX;

    // XCD-chunked swizzle: total blocks % 8 == 0 (2048) -> bijective.
    const int nyt     = IMG_H / TH;                 // 128 y-tiles per image
    const int per_xcd = gridDim.x >> 3;             // 256
    const int lin     = (blockIdx.x & 7) * per_xcd + (blockIdx.x >> 3);
    const int img     = lin / nyt;
    const int yt      = lin - img * nyt;
    const int y0      = yt * TH;

    const size_t base = (size_t)img * (size_t)(IMG_W * IMG_H);
    const float* __restrict__ P = pred + base;
    const float* __restrict__ T = tgt + base;

    // Wave-uniform clamped strip-edge addresses (strip = 256 px per wave).
    const int xs  = (tid >> 6) * (64 * VX);         // strip base pixel
    const int xsl = (xs > 0) ? xs - 1 : 0;
    const int xsr = (xs + 64 * VX < IMG_W) ? xs + 64 * VX : IMG_W - 1;

    float ssim_acc = 0.f, l1_acc = 0.f;
    RowS AB, Bp;
    RowBuf b0, b1, b2, b3, b4, b5;
    float pv[6], tv[6];

#define LOADR(bb, rr) \
    load_rowb(P + (size_t)(rr) * IMG_W, T + (size_t)(rr) * IMG_W, x, xsl, xsr, bb)

    // ---- pre: rows y0-1 .. y0+2 -> B0..B3 ----
    LOADR(b0, (y0 > 0 ? y0 - 1 : 0));   // clamped; discarded via rzero if y0==0
    LOADR(b1, y0);
    LOADR(b2, y0 + 1);
    LOADR(b3, y0 + 2);
    PIN();

    // ---- S0: issue y0+3,y0+4 -> B4,B5 ; consume B0,B1 (prologue rows) ----
    LOADR(b4, y0 + 3);
    LOADR(b5, y0 + 4);
    PIN();
    if (y0 > 0) {
        expand6(b0, lane, x, pv, tv);
        hsum(pv, tv, AB);
    } else {
        rzero(AB);
    }
    expand6(b1, lane, x, pv, tv);
    hsum(pv, tv, Bp);
    add_l1(pv, tv, l1_acc);
#pragma unroll
    for (int j = 0; j < VX; ++j) {
        AB.p[j]  += Bp.p[j];  AB.t[j]  += Bp.t[j];
        AB.pp[j] += Bp.pp[j]; AB.tt[j] += Bp.tt[j]; AB.pt[j] += Bp.pt[j];
    }

    // ---- S1: issue y0+5,y0+6 -> B0,B1 ; consume B2,B3 (rows y0+1,y0+2) ----
    LOADR(b0, y0 + 5);
    LOADR(b1, y0 + 6);
    PIN();
    expand6(b2, lane, x, pv, tv);
    add_l1(pv, tv, l1_acc);
    compute_row(pv, tv, AB, Bp, ssim_acc);    // out row y0
    expand6(b3, lane, x, pv, tv);
    add_l1(pv, tv, l1_acc);
    compute_row(pv, tv, AB, Bp, ssim_acc);    // out row y0+1

    // ---- S2: issue y0+7,(y0+8) -> B2,B3 ; consume B4,B5 (rows y0+3,y0+4) ----
    LOADR(b2, y0 + 7);
    if (y0 + TH < IMG_H) {
        LOADR(b3, y0 + TH);              // bottom halo row
    } else {
        zero_rowb(b3);                   // image bottom: zero-pad (uniform)
    }
    PIN();
    expand6(b4, lane, x, pv, tv);
    add_l1(pv, tv, l1_acc);
    compute_row(pv, tv, AB, Bp, ssim_acc);    // out row y0+2
    expand6(b5, lane, x, pv, tv);
    add_l1(pv, tv, l1_acc);
    compute_row(pv, tv, AB, Bp, ssim_acc);    // out row y0+3

    // ---- S3: consume B0,B1 (rows y0+5,y0+6) ----
    expand6(b0, lane, x, pv, tv);
    add_l1(pv, tv, l1_acc);
    compute_row(pv, tv, AB, Bp, ssim_acc);    // out row y0+4
    expand6(b1, lane, x, pv, tv);
    add_l1(pv, tv, l1_acc);
    compute_row(pv, tv, AB, Bp, ssim_acc);    // out row y0+5

    // ---- S4: consume B2,B3 (rows y0+7, y0+8-halo) ----
    expand6(b2, lane, x, pv, tv);
    add_l1(pv, tv, l1_acc);
    compute_row(pv, tv, AB, Bp, ssim_acc);    // out row y0+6
    if (y0 + TH < IMG_H) {
        expand6(b3, lane, x, pv, tv);
    } else {
#pragma unroll
        for (int k = 0; k < 6; ++k) { pv[k] = 0.f; tv[k] = 0.f; }
    }
    compute_row(pv, tv, AB, Bp, ssim_acc);    // out row y0+7 (halo: no l1)

#undef LOADR

    // --- reduction: wave shuffle -> LDS across 4 waves -> one write/block ---
    float s = ssim_acc, l = l1_acc;
#pragma unroll
    for (int off = 32; off > 0; off >>= 1) {
        s += __shfl_down(s, off, 64);
        l += __shfl_down(l, off, 64);
    }
    __shared__ float red_s[NTHREADS / 64];
    __shared__ float red_l[NTHREADS / 64];
    const int wid = tid >> 6;
    if (lane == 0) { red_s[wid] = s; red_l[wid] = l; }
    __syncthreads();
    if (tid == 0) {
        float ss = 0.f, ll = 0.f;
#pragma unroll
        for (int w = 0; w < NTHREADS / 64; ++w) { ss += red_s[w]; ll += red_l[w]; }
        if (MODE == 0) {
            ws[2 * lin]     = ss;   // lin is bijective: every slot written
            ws[2 * lin + 1] = ll;
        } else {
            atomicAdd(&ws[0], ss);
            atomicAdd(&ws[1], ll);
        }
    }
}

__global__ void zero_ws_kernel(float* __restrict__ ws) {
    ws[0] = 0.f;
    ws[1] = 0.f;
}

// Sum nblocks (ssim,l1) pairs from ws and emit the final scalar.
__global__ void __launch_bounds__(256)
finalize_partials_kernel(const float* __restrict__ ws, float* __restrict__ out,
                         int nblocks, float inv_total) {
    const int tid = threadIdx.x;
    float s = 0.f, l = 0.f;
    for (int i = tid; i < nblocks; i += 256) {
        s += ws[2 * i];
        l += ws[2 * i + 1];
    }
#pragma unroll
    for (int off = 32; off > 0; off >>= 1) {
        s += __shfl_down(s, off, 64);
        l += __shfl_down(l, off, 64);
    }
    __shared__ float red_s[4], red_l[4];
    const int wid = tid >> 6, lane = tid & 63;
    if (lane == 0) { red_s[wid] = s; red_l[wid] = l; }
    __syncthreads();
    if (tid == 0) {
        float ss = red_s[0] + red_s[1] + red_s[2] + red_s[3];
        float ll = red_l[0] + red_l[1] + red_l[2] + red_l[3];
        out[0] = ALPHA_ * (ss * inv_total) + BETA_ * (ll * inv_total);
    }
}

__global__ void finalize_atomic_kernel(const float* __restrict__ ws,
                                       float* __restrict__ out, float inv_total) {
    out[0] = ALPHA_ * (ws[0] * inv_total) + BETA_ * (ws[1] * inv_total);
}

extern "C" void kernel_launch(void* const* d_in, const int* in_sizes, int n_in,
                              void* d_out, int out_size, void* d_ws, size_t ws_size,
                              hipStream_t stream) {
    const float* pred = (const float*)d_in[0];
    const float* tgt  = (const float*)d_in[1];
    float* ws = (float*)d_ws;

    const int total = in_sizes[0];                 // N * H * W = 16 * 1024 * 1024
    const int nimg  = total / (IMG_W * IMG_H);     // 16
    const int nblk  = nimg * (IMG_H / TH);         // 16 * 128 = 2048
    const float inv_total = 1.0f / (float)total;

    dim3 grid(nblk, 1, 1);                         // 1D for XCD swizzle

    if (ws_size >= (size_t)(2 * nblk) * sizeof(float)) {
        // partials path: no pre-zero, no atomics
        ssim_l1_kernel<0><<<grid, NTHREADS, 0, stream>>>(pred, tgt, ws);
        finalize_partials_kernel<<<1, 256, 0, stream>>>(ws, (float*)d_out,
                                                        nblk, inv_total);
    } else {
        // fallback: atomic accumulation into ws[0..1]
        zero_ws_kernel<<<1, 1, 0, stream>>>(ws);
        ssim_l1_kernel<1><<<grid, NTHREADS, 0, stream>>>(pred, tgt, ws);
        finalize_atomic_kernel<<<1, 1, 0, stream>>>(ws, (float*)d_out, inv_total);
    }
}

// Round 8
// 153.137 us; speedup vs baseline: 1.0186x; 1.0186x over previous
//
#include <hip/hip_runtime.h>
#include <hip/hip_bf16.h>

#define IMG_W 1024
#define IMG_H 1024
#define TH    8            // output rows per block: 2048 blocks
#define NROWS (TH + 2)     // staged rows incl. top/bottom halo
#define VX    4            // pixels per thread (float4)
#define NTHREADS 256       // full row width per block

#define ALPHA_ 0.85f
#define BETA_  0.15f
#define C1_    (0.01f * 0.01f)
#define C2_    (0.03f * 0.03f)

// Sums-domain SSIM constants (numerator/denominator both scaled by 81).
#define K1_   (81.0f * C1_)          // 0.0081
#define K2_   (81.0f * C2_)          // 0.0729
#define K12_  (K1_ + K2_)            // 0.081

// Per-row horizontal 3-sum stats for VX pixels: 20 floats.
struct RowS { float p[VX], t[VX], pp[VX], tt[VX], pt[VX]; };

__device__ __forceinline__ void rzero(RowS& h) {
#pragma unroll
    for (int j = 0; j < VX; ++j) {
        h.p[j] = 0.f; h.t[j] = 0.f; h.pp[j] = 0.f; h.tt[j] = 0.f; h.pt[j] = 0.f;
    }
}

// Expand one staged LDS row into the 6-wide window.
// Vector body: ds_read_b128. Halo: lane shuffles (bpermute, no LDS storage
// access) + WAVE-UNIFORM broadcast ds_read_b32 for the two strip edges
// (same-address across lanes = broadcast, no conflict). NO strided b32
// reads (R3's 2M bank-conflict cycles came from those).
__device__ __forceinline__ void expand_lds(const float* __restrict__ rowp,
                                           const float* __restrict__ rowt,
                                           int x, int lane, int xsl, int xsr,
                                           float pv[6], float tv[6]) {
    const float4 p4 = *reinterpret_cast<const float4*>(rowp + x);
    const float4 t4 = *reinterpret_cast<const float4*>(rowt + x);
    pv[1] = p4.x; pv[2] = p4.y; pv[3] = p4.z; pv[4] = p4.w;
    tv[1] = t4.x; tv[2] = t4.y; tv[3] = t4.z; tv[4] = t4.w;
    const float pl = rowp[xsl], tl = rowt[xsl];   // broadcast reads
    const float pr = rowp[xsr], tr = rowt[xsr];
    const float pu = __shfl_up(p4.w, 1, 64);
    const float tu = __shfl_up(t4.w, 1, 64);
    const float pd = __shfl_down(p4.x, 1, 64);
    const float td = __shfl_down(t4.x, 1, 64);
    pv[0] = (lane == 0)  ? pl : pu;
    tv[0] = (lane == 0)  ? tl : tu;
    pv[5] = (lane == 63) ? pr : pd;
    tv[5] = (lane == 63) ? tr : td;
    if (x == 0)          { pv[0] = 0.f; tv[0] = 0.f; }   // image left edge
    if (x + VX >= IMG_W) { pv[5] = 0.f; tv[5] = 0.f; }   // image right edge
}

__device__ __forceinline__ void hsum(const float pv[6], const float tv[6], RowS& h) {
#pragma unroll
    for (int j = 0; j < VX; ++j) {
        const float a = pv[j], b = pv[j + 1], c = pv[j + 2];
        const float u = tv[j], v = tv[j + 1], w = tv[j + 2];
        h.p[j]  = a + b + c;
        h.t[j]  = u + v + w;
        h.pp[j] = a * a + b * b + c * c;
        h.tt[j] = u * u + v * v + w * w;
        h.pt[j] = a * u + b * v + c * w;
    }
}

__device__ __forceinline__ void add_l1(const float pv[6], const float tv[6],
                                       float& l1_acc) {
#pragma unroll
    for (int k = 1; k <= VX; ++k) l1_acc += fabsf(pv[k] - tv[k]);
}

// Consume one row: emit SSIM for the output row above it and roll the
// vertical window state (AB = rowstats(y-1)+rowstats(y), Bp = rowstats(y)).
__device__ __forceinline__ void compute_row(const float pv[6], const float tv[6],
                                            RowS& AB, RowS& Bp, float& ssim_acc) {
#pragma unroll
    for (int j = 0; j < VX; ++j) {
        const float a = pv[j], b = pv[j + 1], c = pv[j + 2];
        const float u = tv[j], v = tv[j + 1], w = tv[j + 2];
        const float cp  = a + b + c;
        const float ct  = u + v + w;
        const float cpp = a * a + b * b + c * c;
        const float ctt = u * u + v * v + w * w;
        const float cpt = a * u + b * v + c * w;

        const float Sp  = AB.p[j]  + cp;
        const float St  = AB.t[j]  + ct;
        const float Spp = AB.pp[j] + cpp;
        const float Stt = AB.tt[j] + ctt;
        const float Spt = AB.pt[j] + cpt;

        AB.p[j]  = Bp.p[j]  + cp;  Bp.p[j]  = cp;
        AB.t[j]  = Bp.t[j]  + ct;  Bp.t[j]  = ct;
        AB.pp[j] = Bp.pp[j] + cpp; Bp.pp[j] = cpp;
        AB.tt[j] = Bp.tt[j] + ctt; Bp.tt[j] = ctt;
        AB.pt[j] = Bp.pt[j] + cpt; Bp.pt[j] = cpt;

        // sums-domain SSIM (x81^2 in both numerator and denominator)
        const float SpSt = Sp * St;
        const float A2 = fmaf(2.0f, SpSt, K1_);
        const float B2 = fmaf(-2.0f, SpSt, fmaf(18.0f, Spt, K2_));
        const float n  = A2 * B2;
        const float D1 = fmaf(Sp, Sp, fmaf(St, St, K1_));
        const float D2 = fmaf(9.0f, Spp + Stt, K12_) - D1;
        const float d  = D1 * D2;
        const float ssim = n * __builtin_amdgcn_rcpf(d);  // d >= 81^2*C1*C2 > 0
        float vcl = fmaf(-0.5f, ssim, 0.5f);
        vcl = fminf(fmaxf(vcl, 0.0f), 1.0f);
        ssim_acc += vcl;
    }
}

// R8: monolithic global_load_lds burst. The ONLY prefetch mechanism the
// register allocator cannot collapse (no VGPR destination): 20 DMAs (10 rows
// x 2 tensors, 80 KB) issued back-to-back, ONE __syncthreads (= vmcnt(0)
// drain + barrier), then pure-LDS compute.
//  - R3's failure causes fixed: no strided b32 LDS reads (shuffle halo +
//    uniform broadcast edges); 1 barrier instead of 10 phase barriers.
//  - 80 KB -> exactly 2 blocks/CU: block B's DMA overlaps block A's compute
//    with no intra-block phase discipline.
//  - XCD-chunked bijective swizzle kept (R7: FETCH 84->66 MB, proven).
// Reduction reuses pbuf (no extra LDS; 2x81920 = 160 KB exactly).
template <int MODE>
__global__ void __launch_bounds__(NTHREADS)
ssim_l1_kernel(const float* __restrict__ pred, const float* __restrict__ tgt,
               float* __restrict__ ws) {
    __shared__ __align__(16) float pbuf[NROWS][IMG_W];
    __shared__ __align__(16) float tbuf[NROWS][IMG_W];

    const int tid  = threadIdx.x;
    const int lane = tid & 63;
    const int wid  = tid >> 6;
    const int x    = tid * VX;

    // XCD-chunked swizzle: 2048 % 8 == 0 -> bijective.
    const int nyt     = IMG_H / TH;                 // 128 y-tiles per image
    const int per_xcd = gridDim.x >> 3;
    const int lin     = (blockIdx.x & 7) * per_xcd + (blockIdx.x >> 3);
    const int img     = lin / nyt;
    const int yt      = lin - img * nyt;
    const int y0      = yt * TH;

    const size_t base = (size_t)img * (size_t)(IMG_W * IMG_H);
    const float* __restrict__ P = pred + base;
    const float* __restrict__ T = tgt + base;

    const int wq = wid * (64 * VX);                 // wave strip base (floats)

    // ---- monolithic DMA burst: all NROWS rows of P and T, no waits ----
#pragma unroll
    for (int k = 0; k < NROWS; ++k) {
        int ry = y0 - 1 + k;                        // clamp (top/bottom halo)
        ry = (ry < 0) ? 0 : ((ry > IMG_H - 1) ? IMG_H - 1 : ry);
        const float* gp = P + (size_t)ry * IMG_W + x;
        const float* gt = T + (size_t)ry * IMG_W + x;
        __builtin_amdgcn_global_load_lds(
            (const __attribute__((address_space(1))) void*)gp,
            (__attribute__((address_space(3))) void*)(&pbuf[k][wq]), 16, 0, 0);
        __builtin_amdgcn_global_load_lds(
            (const __attribute__((address_space(1))) void*)gt,
            (__attribute__((address_space(3))) void*)(&tbuf[k][wq]), 16, 0, 0);
    }
    __syncthreads();   // vmcnt(0)+lgkmcnt(0)+barrier: all 80 KB resident

    // Wave-uniform clamped strip-edge addresses (strip = 256 px per wave).
    const int xsl = (wq > 0) ? wq - 1 : 0;
    const int xsr = (wq + 64 * VX < IMG_W) ? wq + 64 * VX : IMG_W - 1;

    float ssim_acc = 0.f, l1_acc = 0.f;
    RowS AB, Bp;
    float pv[6], tv[6];

    // ---- prologue: slot 0 (top halo) -> AB ; slot 1 (row y0) -> Bp ----
    if (y0 > 0) {
        expand_lds(&pbuf[0][0], &tbuf[0][0], x, lane, xsl, xsr, pv, tv);
        hsum(pv, tv, AB);
    } else {
        rzero(AB);
    }
    expand_lds(&pbuf[1][0], &tbuf[1][0], x, lane, xsl, xsr, pv, tv);
    hsum(pv, tv, Bp);
    add_l1(pv, tv, l1_acc);
#pragma unroll
    for (int j = 0; j < VX; ++j) {
        AB.p[j]  += Bp.p[j];  AB.t[j]  += Bp.t[j];
        AB.pp[j] += Bp.pp[j]; AB.tt[j] += Bp.tt[j]; AB.pt[j] += Bp.pt[j];
    }

    // ---- slots 2..NROWS-2: rows y0+1..y0+7 -> out rows y0..y0+6, l1 ----
#pragma unroll
    for (int r = 2; r <= NROWS - 2; ++r) {
        expand_lds(&pbuf[r][0], &tbuf[r][0], x, lane, xsl, xsr, pv, tv);
        add_l1(pv, tv, l1_acc);
        compute_row(pv, tv, AB, Bp, ssim_acc);
    }

    // ---- slot NROWS-1: bottom halo row y0+8 -> out row y0+7 (no l1) ----
    if (y0 + TH < IMG_H) {
        expand_lds(&pbuf[NROWS - 1][0], &tbuf[NROWS - 1][0], x, lane, xsl, xsr,
                   pv, tv);
    } else {
#pragma unroll
        for (int k = 0; k < 6; ++k) { pv[k] = 0.f; tv[k] = 0.f; }
    }
    compute_row(pv, tv, AB, Bp, ssim_acc);

    // --- reduction: wave shuffle -> LDS (reuse pbuf) -> one write/block ---
    float s = ssim_acc, l = l1_acc;
#pragma unroll
    for (int off = 32; off > 0; off >>= 1) {
        s += __shfl_down(s, off, 64);
        l += __shfl_down(l, off, 64);
    }
    __syncthreads();                  // all row reads done before pbuf reuse
    if (lane == 0) { pbuf[0][wid] = s; pbuf[0][8 + wid] = l; }
    __syncthreads();
    if (tid == 0) {
        float ss = 0.f, ll = 0.f;
#pragma unroll
        for (int w = 0; w < NTHREADS / 64; ++w) {
            ss += pbuf[0][w]; ll += pbuf[0][8 + w];
        }
        if (MODE == 0) {
            ws[2 * lin]     = ss;     // lin bijective: every slot written
            ws[2 * lin + 1] = ll;
        } else {
            atomicAdd(&ws[0], ss);
            atomicAdd(&ws[1], ll);
        }
    }
}

__global__ void zero_ws_kernel(float* __restrict__ ws) {
    ws[0] = 0.f;
    ws[1] = 0.f;
}

// Sum nblocks (ssim,l1) pairs from ws and emit the final scalar.
__global__ void __launch_bounds__(256)
finalize_partials_kernel(const float* __restrict__ ws, float* __restrict__ out,
                         int nblocks, float inv_total) {
    const int tid = threadIdx.x;
    float s = 0.f, l = 0.f;
    for (int i = tid; i < nblocks; i += 256) {
        s += ws[2 * i];
        l += ws[2 * i + 1];
    }
#pragma unroll
    for (int off = 32; off > 0; off >>= 1) {
        s += __shfl_down(s, off, 64);
        l += __shfl_down(l, off, 64);
    }
    __shared__ float red_s[4], red_l[4];
    const int wid = tid >> 6, lane = tid & 63;
    if (lane == 0) { red_s[wid] = s; red_l[wid] = l; }
    __syncthreads();
    if (tid == 0) {
        float ss = red_s[0] + red_s[1] + red_s[2] + red_s[3];
        float ll = red_l[0] + red_l[1] + red_l[2] + red_l[3];
        out[0] = ALPHA_ * (ss * inv_total) + BETA_ * (ll * inv_total);
    }
}

__global__ void finalize_atomic_kernel(const float* __restrict__ ws,
                                       float* __restrict__ out, float inv_total) {
    out[0] = ALPHA_ * (ws[0] * inv_total) + BETA_ * (ws[1] * inv_total);
}

extern "C" void kernel_launch(void* const* d_in, const int* in_sizes, int n_in,
                              void* d_out, int out_size, void* d_ws, size_t ws_size,
                              hipStream_t stream) {
    const float* pred = (const float*)d_in[0];
    const float* tgt  = (const float*)d_in[1];
    float* ws = (float*)d_ws;

    const int total = in_sizes[0];                 // N * H * W = 16 * 1024 * 1024
    const int nimg  = total / (IMG_W * IMG_H);     // 16
    const int nblk  = nimg * (IMG_H / TH);         // 16 * 128 = 2048
    const float inv_total = 1.0f / (float)total;

    dim3 grid(nblk, 1, 1);                         // 1D for XCD swizzle

    if (ws_size >= (size_t)(2 * nblk) * sizeof(float)) {
        // partials path: no pre-zero, no atomics
        ssim_l1_kernel<0><<<grid, NTHREADS, 0, stream>>>(pred, tgt, ws);
        finalize_partials_kernel<<<1, 256, 0, stream>>>(ws, (float*)d_out,
                                                        nblk, inv_total);
    } else {
        // fallback: atomic accumulation into ws[0..1]
        zero_ws_kernel<<<1, 1, 0, stream>>>(ws);
        ssim_l1_kernel<1><<<grid, NTHREADS, 0, stream>>>(pred, tgt, ws);
        finalize_atomic_kernel<<<1, 1, 0, stream>>>(ws, (float*)d_out, inv_total);
    }
}